// Round 4
// baseline (342.198 us; speedup 1.0000x reference)
//
#include <hip/hip_runtime.h>
#include <stdint.h>

// Problem constants (fixed by the reference): x is (128,1,512,512) fp32, k=2048.
#define B        128
#define ROW_N    262144                 // 512*512 elements per row
#define NBUCKET  4096                   // 12-bit key buckets
#define KSHIFT   19                     // (bits & 0x7FFFFFFF) >> 19 -> 0..4095
#define THREADS  256
#define BLOCKS_PER_ROW 8
#define BLK_CHUNK (ROW_N / BLOCKS_PER_ROW)   // 32768 floats per block
#define STAGE_F  4096                        // floats staged per iteration (16 KiB)
#define NITER    (BLK_CHUNK / STAGE_F)       // 8

// Speculative pre-filter: collect all elements with |x| >= 2.0 (bucket 2048).
// For the fixed N(0,1) input the k-th |x| ~= 2.66 (bucket ~2052) and the >=2.0
// population is ~11.9k +- 107 per row. Exactness NEVER depends on this: the
// histogram is exact, and any violation sets row_flag -> exact fallback pass.
#define B0_BUCKET     2048
#define CAND_CAP      16384   // per-row candidate capacity (~38 sigma margin)
#define ITER_CAND_CAP 768     // per-block-iteration LDS capacity (mean ~186)
#define TIE_CAP       2048    // scatter-pass tie buffer (mean ~950)
#define FB_TIE_CAP    4096    // fallback tie buffer

// workspace layout (bytes)
#define OFF_HIST 0
#define SZ_HIST  (B * NBUCKET * 4)          // 2 MiB
#define OFF_CNT  (OFF_HIST + SZ_HIST)       // per-row candidate counters (B u32)
#define OFF_OFL  (OFF_CNT + 512)            // per-row iter-overflow flags (B u32)
#define OFF_BKT  (OFF_OFL + 512)            // per-row threshold bucket (B int)
#define OFF_NEED (OFF_BKT + 512)            // per-row remaining count (B int)
#define OFF_FLG  (OFF_NEED + 512)           // per-row fallback flag (B int)
#define OFF_CAND (OFF_FLG + 512)            // B * CAND_CAP * uint2 = 16 MiB
#define MEMSET_BYTES (SZ_HIST + 1024)       // hist + cand_count + oflow

// async global->LDS copy, 16 B per lane (wave-uniform base + lane*16 mapping).
__device__ __forceinline__ void g2l16(const float* g, float* l) {
    __builtin_amdgcn_global_load_lds(
        (const __attribute__((address_space(1))) void*)g,
        (__attribute__((address_space(3))) void*)l, 16, 0, 0);
}

// -- pass A: the ONLY full read. hist + zero-fill out + compact candidates. ----
__global__ __launch_bounds__(THREADS) void passA_kernel(const float* __restrict__ x,
                                                        float* __restrict__ out,
                                                        unsigned* __restrict__ hist,
                                                        unsigned* __restrict__ cand_count,
                                                        unsigned* __restrict__ row_oflow,
                                                        uint2* __restrict__ cand) {
    __shared__ float stage[STAGE_F];            // 16 KiB
    __shared__ unsigned h[NBUCKET];             // 16 KiB
    __shared__ unsigned cidx[ITER_CAND_CAP];    // 3 KiB
    __shared__ unsigned cbits[ITER_CAND_CAP];   // 3 KiB
    __shared__ unsigned ccnt, cbase, nflush;
    const int t = threadIdx.x;
    for (int i = t; i < NBUCKET; i += THREADS) h[i] = 0;
    if (t == 0) ccnt = 0;
    const int row = blockIdx.y;
    const int chunk0 = blockIdx.x * BLK_CHUNK;
    const float* src = x + (size_t)row * ROW_N + chunk0;
    float* dst = out + (size_t)row * ROW_N + chunk0;
    uint2* rcand = cand + (size_t)row * CAND_CAP;
    __syncthreads();

    for (int it = 0; it < NITER; ++it) {
        const int ibase = it * STAGE_F;
#pragma unroll
        for (int q = 0; q < 4; ++q)
            g2l16(src + ibase + q * 1024 + t * 4, &stage[q * 1024 + t * 4]);
        // zero-fill this out tile while the staging loads are in flight
        const float4 z = make_float4(0.f, 0.f, 0.f, 0.f);
#pragma unroll
        for (int q = 0; q < 4; ++q)
            ((float4*)(dst + ibase))[q * THREADS + t] = z;
        __syncthreads();   // drains vmcnt(0): staged data valid
#pragma unroll
        for (int q = 0; q < 4; ++q) {
            const int off = q * 1024 + t * 4;
            const float4 v = *(const float4*)&stage[off];
            const unsigned bits4[4] = {__float_as_uint(v.x), __float_as_uint(v.y),
                                       __float_as_uint(v.z), __float_as_uint(v.w)};
#pragma unroll
            for (int c = 0; c < 4; ++c) {
                const unsigned key = (bits4[c] & 0x7FFFFFFFu) >> KSHIFT;
                atomicAdd(&h[key], 1u);
                if (key >= B0_BUCKET) {   // ~4.5% of elements
                    const unsigned p = atomicAdd(&ccnt, 1u);
                    if (p < ITER_CAND_CAP) {
                        cidx[p]  = (unsigned)(chunk0 + ibase + off + c);
                        cbits[p] = bits4[c];
                    }
                }
            }
        }
        __syncthreads();   // all appends done
        if (t == 0) {
            const unsigned n = ccnt;
            nflush = n < ITER_CAND_CAP ? n : ITER_CAND_CAP;
            cbase = atomicAdd(&cand_count[row], n);  // true count (overflow detect)
            if (n > ITER_CAND_CAP) row_oflow[row] = 1u;
            ccnt = 0;
        }
        __syncthreads();   // cbase/nflush visible; ccnt reset before next appends
        for (unsigned i = (unsigned)t; i < nflush; i += THREADS) {
            const unsigned g = cbase + i;
            if (g < CAND_CAP) rcand[g] = make_uint2(cidx[i], cbits[i]);
        }
        // next iteration's appends only start after its own post-stage barrier
    }

    unsigned* gh = hist + (size_t)row * NBUCKET;
    for (int i = t; i < NBUCKET; i += THREADS) {
        const unsigned c = h[i];
        if (c) atomicAdd(&gh[i], c);
    }
}

// -------- select: per-row suffix scan from top bucket; exact threshold --------
__global__ __launch_bounds__(THREADS) void select_kernel(const unsigned* __restrict__ hist,
                                                         const int* __restrict__ topk,
                                                         const unsigned* __restrict__ cand_count,
                                                         const unsigned* __restrict__ row_oflow,
                                                         int* __restrict__ row_bucket,
                                                         int* __restrict__ row_need,
                                                         int* __restrict__ row_flag) {
    const int row = blockIdx.x;
    const int t = threadIdx.x;
    const unsigned K = (unsigned)(*topk);
    const unsigned* gh = hist + (size_t)row * NBUCKET;

    __shared__ unsigned partial[THREADS];
    __shared__ unsigned excl[THREADS];
    const int PER = NBUCKET / THREADS;  // 16 buckets per thread, descending order
    unsigned s = 0;
#pragma unroll
    for (int i = 0; i < PER; ++i) s += gh[NBUCKET - 1 - (t * PER + i)];
    partial[t] = s;
    __syncthreads();
    if (t == 0) {
        unsigned c = 0;
        for (int i = 0; i < THREADS; ++i) { excl[i] = c; c += partial[i]; }
    }
    __syncthreads();

    unsigned cum = excl[t];
#pragma unroll
    for (int i = 0; i < PER; ++i) {
        const int bucket = NBUCKET - 1 - (t * PER + i);
        const unsigned c = gh[bucket];
        if (cum < K && cum + c >= K) {   // unique crossing thread/iteration
            row_bucket[row] = bucket;
            row_need[row]   = (int)(K - cum);
            const bool bad = (bucket < B0_BUCKET) ||
                             (cand_count[row] > (unsigned)CAND_CAP) ||
                             (c > (unsigned)TIE_CAP) ||
                             (row_oflow[row] != 0u);
            row_flag[row] = bad ? 1 : 0;
        }
        cum += c;
    }
}

// ---- scatter: sparse pass over candidates only; exact tie-rank in LDS --------
__global__ __launch_bounds__(THREADS) void scatter_kernel(float* __restrict__ out,
                                                          const uint2* __restrict__ cand,
                                                          const unsigned* __restrict__ cand_count,
                                                          const int* __restrict__ row_bucket,
                                                          const int* __restrict__ row_need,
                                                          const int* __restrict__ row_flag) {
    const int row = blockIdx.x;
    if (row_flag[row]) return;   // fallback pass owns this row
    const int t = threadIdx.x;
    const int b = row_bucket[row];
    const int need = row_need[row];
    const unsigned n = cand_count[row];   // <= CAND_CAP (else flagged)
    const uint2* rc = cand + (size_t)row * CAND_CAP;
    float* rout = out + (size_t)row * ROW_N;

    __shared__ unsigned tidx[TIE_CAP];    // 8 KiB
    __shared__ unsigned tbits[TIE_CAP];   // 8 KiB
    __shared__ unsigned tcnt;
    if (t == 0) tcnt = 0;
    __syncthreads();

    for (unsigned i = (unsigned)t; i < n; i += THREADS) {
        const uint2 e = rc[i];
        const int key = (int)((e.y & 0x7FFFFFFFu) >> KSHIFT);
        if (key > b) {
            rout[e.x] = __uint_as_float(e.y);
        } else if (key == b) {
            const unsigned p = atomicAdd(&tcnt, 1u);
            if (p < TIE_CAP) { tidx[p] = e.x; tbits[p] = e.y; }
        }
    }
    __syncthreads();
    const int c = (int)(tcnt < (unsigned)TIE_CAP ? tcnt : (unsigned)TIE_CAP);
    for (int i = t; i < c; i += THREADS) {
        const unsigned bits = tbits[i], idx = tidx[i];
        const uint64_t key = ((uint64_t)(bits & 0x7FFFFFFFu) << 32) | (uint64_t)(~idx);
        int rank = 0;
        for (int j = 0; j < c; ++j) {
            const uint64_t kj = ((uint64_t)(tbits[j] & 0x7FFFFFFFu) << 32) | (uint64_t)(~tidx[j]);
            rank += (kj > key) ? 1 : 0;
        }
        if (rank < need) rout[idx] = __uint_as_float(bits);
    }
}

// ---- fallback: exact full-row solve for flagged rows (normally a no-op) ------
__global__ __launch_bounds__(THREADS) void fallback_kernel(const float* __restrict__ x,
                                                           float* __restrict__ out,
                                                           const int* __restrict__ row_bucket,
                                                           const int* __restrict__ row_need,
                                                           const int* __restrict__ row_flag) {
    const int row = blockIdx.x;
    if (!row_flag[row]) return;
    const int t = threadIdx.x;
    const int b = row_bucket[row];
    const int need = row_need[row];
    const float4* xr = (const float4*)(x + (size_t)row * ROW_N);
    float* rout = out + (size_t)row * ROW_N;

    __shared__ unsigned tidx[FB_TIE_CAP];    // 16 KiB
    __shared__ unsigned tbits[FB_TIE_CAP];   // 16 KiB
    __shared__ unsigned tcnt;
    if (t == 0) tcnt = 0;
    __syncthreads();

    for (int i4 = t; i4 < ROW_N / 4; i4 += THREADS) {
        const float4 v = xr[i4];
        const unsigned bits4[4] = {__float_as_uint(v.x), __float_as_uint(v.y),
                                   __float_as_uint(v.z), __float_as_uint(v.w)};
#pragma unroll
        for (int c = 0; c < 4; ++c) {
            const int key = (int)((bits4[c] & 0x7FFFFFFFu) >> KSHIFT);
            if (key > b) {
                rout[i4 * 4 + c] = __uint_as_float(bits4[c]);
            } else if (key == b) {
                const unsigned p = atomicAdd(&tcnt, 1u);
                if (p < FB_TIE_CAP) { tidx[p] = (unsigned)(i4 * 4 + c); tbits[p] = bits4[c]; }
            }
        }
    }
    __syncthreads();
    const int c = (int)(tcnt < (unsigned)FB_TIE_CAP ? tcnt : (unsigned)FB_TIE_CAP);
    for (int i = t; i < c; i += THREADS) {
        const unsigned bits = tbits[i], idx = tidx[i];
        const uint64_t key = ((uint64_t)(bits & 0x7FFFFFFFu) << 32) | (uint64_t)(~idx);
        int rank = 0;
        for (int j = 0; j < c; ++j) {
            const uint64_t kj = ((uint64_t)(tbits[j] & 0x7FFFFFFFu) << 32) | (uint64_t)(~tidx[j]);
            rank += (kj > key) ? 1 : 0;
        }
        if (rank < need) rout[idx] = __uint_as_float(bits);
    }
}

extern "C" void kernel_launch(void* const* d_in, const int* in_sizes, int n_in,
                              void* d_out, int out_size, void* d_ws, size_t ws_size,
                              hipStream_t stream) {
    const float* x = (const float*)d_in[0];
    const int* topk = (const int*)d_in[1];
    float* out = (float*)d_out;
    char* ws = (char*)d_ws;

    unsigned* hist       = (unsigned*)(ws + OFF_HIST);
    unsigned* cand_count = (unsigned*)(ws + OFF_CNT);
    unsigned* row_oflow  = (unsigned*)(ws + OFF_OFL);
    int* row_bucket      = (int*)(ws + OFF_BKT);
    int* row_need        = (int*)(ws + OFF_NEED);
    int* row_flag        = (int*)(ws + OFF_FLG);
    uint2* cand          = (uint2*)(ws + OFF_CAND);

    // zero hist + counters (ws is re-poisoned to 0xAA before each run)
    hipMemsetAsync(ws, 0, MEMSET_BYTES, stream);

    dim3 gridA(BLOCKS_PER_ROW, B);  // 8 x 128 = 1024 blocks, 4/CU
    passA_kernel<<<gridA, THREADS, 0, stream>>>(x, out, hist, cand_count, row_oflow, cand);
    select_kernel<<<B, THREADS, 0, stream>>>(hist, topk, cand_count, row_oflow,
                                             row_bucket, row_need, row_flag);
    scatter_kernel<<<B, THREADS, 0, stream>>>(out, cand, cand_count,
                                              row_bucket, row_need, row_flag);
    fallback_kernel<<<B, THREADS, 0, stream>>>(x, out, row_bucket, row_need, row_flag);
}

// Round 5
// 308.848 us; speedup vs baseline: 1.1080x; 1.1080x over previous
//
#include <hip/hip_runtime.h>
#include <stdint.h>

// Problem constants (fixed by the reference): x is (128,1,512,512) fp32, k=2048.
#define B        128
#define ROW_N    262144                 // 512*512 elements per row
#define THREADS  256
#define BLOCKS_PER_ROW 16
#define BLK_CHUNK (ROW_N / BLOCKS_PER_ROW)   // 16384 floats per block
#define STAGE_F  4096                        // floats staged per iteration (16 KiB)
#define NITER    (BLK_CHUNK / STAGE_F)       // 4

// Speculative exact pre-filter: keep ALL elements with |x| >= 2.0.
// For the fixed N(0,1) input: k-th |x| ~= 2.66; >=2.0 population ~11.9k +- 107
// per row (cap 16384 is ~40 sigma; per-iter cap 768 vs mean 184 is ~40 sigma).
// n >= K guarantees the exact top-k lies within the candidate set, so no full
// histogram is needed. Any violation flags the row -> exact fallback pass.
#define B0_BITS  0x40000000u  // bit pattern of 2.0f (abs-bits compare)
#define CAND_CAP 16384        // per-row candidate capacity
#define ITER_CAND_CAP 768     // per-block-iteration LDS capacity
#define FKSHIFT  17           // 14-bit fine key for tie resolution
#define FB0      8192         // (B0_BITS >> FKSHIFT)
#define NFB      8192         // fine buckets [8192, 16384)
#define TIE_CAP  2048         // ties in one fine bucket (mean ~180)
// fallback (normally never runs)
#define KSHIFT   19
#define NBUCKET  4096
#define FB_TIE_CAP 4096

// workspace layout (bytes)
#define OFF_CNT  0                         // per-row candidate counters (B u32)
#define OFF_OFL  512                       // per-row iter-overflow flags (B u32)
#define OFF_FLG  1024                      // per-row fallback flag (B int)
#define OFF_CAND 4096                      // B * CAND_CAP * uint2 = 16 MiB
#define MEMSET_BYTES 1536

// async global->LDS copy, 16 B per lane (wave-uniform base + lane*16 mapping).
__device__ __forceinline__ void g2l16(const float* g, float* l) {
    __builtin_amdgcn_global_load_lds(
        (const __attribute__((address_space(1))) void*)g,
        (__attribute__((address_space(3))) void*)l, 16, 0, 0);
}

// -- pass A: the ONLY full read. zero-fill out + compact |x|>=2 candidates. ----
// No histogram, no per-element LDS atomics: wave-ballot aggregation only.
__global__ __launch_bounds__(THREADS) void passA_kernel(const float* __restrict__ x,
                                                        float* __restrict__ out,
                                                        unsigned* __restrict__ cand_count,
                                                        unsigned* __restrict__ row_oflow,
                                                        uint2* __restrict__ cand) {
    __shared__ float stage[STAGE_F];            // 16 KiB
    __shared__ unsigned cidx[ITER_CAND_CAP];    // 3 KiB
    __shared__ unsigned cbits[ITER_CAND_CAP];   // 3 KiB
    __shared__ unsigned ccnt, cbase, nflush;
    const int t = threadIdx.x;
    const int lane = t & 63;
    const unsigned long long lt_mask = (1ull << lane) - 1ull;
    if (t == 0) ccnt = 0;
    const int row = blockIdx.y;
    const int chunk0 = blockIdx.x * BLK_CHUNK;
    const float* src = x + (size_t)row * ROW_N + chunk0;
    float* dst = out + (size_t)row * ROW_N + chunk0;
    uint2* rcand = cand + (size_t)row * CAND_CAP;
    __syncthreads();

    for (int it = 0; it < NITER; ++it) {
        const int ibase = it * STAGE_F;
#pragma unroll
        for (int q = 0; q < 4; ++q)
            g2l16(src + ibase + q * 1024 + t * 4, &stage[q * 1024 + t * 4]);
        // zero-fill this out tile while the staging DMAs are in flight
        const float4 z = make_float4(0.f, 0.f, 0.f, 0.f);
#pragma unroll
        for (int q = 0; q < 4; ++q)
            ((float4*)(dst + ibase))[q * THREADS + t] = z;
        __syncthreads();   // drains vmcnt(0): staged data valid
#pragma unroll
        for (int q = 0; q < 4; ++q) {
            const int off = q * 1024 + t * 4;
            const float4 v = *(const float4*)&stage[off];
            const unsigned bits4[4] = {__float_as_uint(v.x), __float_as_uint(v.y),
                                       __float_as_uint(v.z), __float_as_uint(v.w)};
#pragma unroll
            for (int c = 0; c < 4; ++c) {
                const bool pred = (bits4[c] & 0x7FFFFFFFu) >= B0_BITS;  // ~4.5%
                const unsigned long long mask = __ballot(pred);
                if (mask) {   // wave-uniform branch
                    const int first = __ffsll((long long)mask) - 1;
                    unsigned wb = 0;
                    if (lane == first)
                        wb = atomicAdd(&ccnt, (unsigned)__popcll(mask));
                    wb = __shfl(wb, first);
                    if (pred) {
                        const unsigned p = wb + (unsigned)__popcll(mask & lt_mask);
                        if (p < ITER_CAND_CAP) {
                            cidx[p]  = (unsigned)(chunk0 + ibase + off + c);
                            cbits[p] = bits4[c];
                        }
                    }
                }
            }
        }
        __syncthreads();   // all appends done
        if (t == 0) {
            const unsigned n = ccnt;
            nflush = n < ITER_CAND_CAP ? n : ITER_CAND_CAP;
            cbase = atomicAdd(&cand_count[row], n);  // true count (overflow detect)
            if (n > ITER_CAND_CAP) row_oflow[row] = 1u;
            ccnt = 0;
        }
        __syncthreads();   // cbase/nflush visible; ccnt reset
        for (unsigned i = (unsigned)t; i < nflush; i += THREADS) {
            const unsigned g = cbase + i;
            if (g < CAND_CAP) rcand[g] = make_uint2(cidx[i], cbits[i]);
        }
        // next iteration's appends start only after its post-stage barrier
    }
}

// -- select+scatter fused: per row, hist over candidates only, exact top-k -----
__global__ __launch_bounds__(THREADS) void select_scatter_kernel(
        const uint2* __restrict__ cand, const unsigned* __restrict__ cand_count,
        const unsigned* __restrict__ row_oflow, const int* __restrict__ topk,
        float* __restrict__ out, int* __restrict__ row_flag) {
    const int row = blockIdx.x;
    const int t = threadIdx.x;
    const unsigned K = (unsigned)(*topk);
    const unsigned n = cand_count[row];
    const unsigned of = row_oflow[row];

    __shared__ unsigned h[NFB];          // 32 KiB fine-bucket hist
    __shared__ unsigned tidx[TIE_CAP];   // 8 KiB
    __shared__ unsigned tbits[TIE_CAP];  // 8 KiB
    __shared__ unsigned partial[THREADS];
    __shared__ unsigned excl[THREADS];
    __shared__ unsigned tcnt;
    __shared__ int sb, sneed;

    if (n < K || n > (unsigned)CAND_CAP || of) {   // block-uniform
        if (t == 0) row_flag[row] = 1;
        return;
    }
    for (int i = t; i < NFB; i += THREADS) h[i] = 0;
    if (t == 0) tcnt = 0;
    __syncthreads();

    const uint2* rc = cand + (size_t)row * CAND_CAP;
    for (unsigned i = (unsigned)t; i < n; i += THREADS) {
        const uint2 e = rc[i];
        atomicAdd(&h[((e.y & 0x7FFFFFFFu) >> FKSHIFT) - FB0], 1u);
    }
    __syncthreads();

    // suffix scan from the top fine bucket
    const int PER = NFB / THREADS;   // 32
    unsigned s = 0;
#pragma unroll
    for (int i = 0; i < PER; ++i) s += h[NFB - 1 - (t * PER + i)];
    partial[t] = s;
    __syncthreads();
    if (t == 0) {
        unsigned c = 0;
        for (int i = 0; i < THREADS; ++i) { excl[i] = c; c += partial[i]; }
    }
    __syncthreads();
    unsigned cum = excl[t];
#pragma unroll
    for (int i = 0; i < PER; ++i) {
        const int brel = NFB - 1 - (t * PER + i);
        const unsigned c = h[brel];
        if (cum < K && cum + c >= K) {   // unique crossing
            sb = brel + FB0;
            sneed = (int)(K - cum);
        }
        cum += c;
    }
    __syncthreads();
    const int b = sb;
    const int need = sneed;
    if (h[b - FB0] > (unsigned)TIE_CAP) {   // block-uniform; before any writes
        if (t == 0) row_flag[row] = 1;
        return;
    }

    // scatter winners above the tie bucket; collect ties
    float* rout = out + (size_t)row * ROW_N;
    for (unsigned i = (unsigned)t; i < n; i += THREADS) {
        const uint2 e = rc[i];
        const int fk = (int)((e.y & 0x7FFFFFFFu) >> FKSHIFT);
        if (fk > b) {
            rout[e.x] = __uint_as_float(e.y);
        } else if (fk == b) {
            const unsigned p = atomicAdd(&tcnt, 1u);
            tidx[p] = e.x; tbits[p] = e.y;   // p < TIE_CAP guaranteed (hist check)
        }
    }
    __syncthreads();

    // exact rank among ties: desc |x| bits, asc index (matches lax.top_k)
    const int c = (int)tcnt;
    for (int i = t; i < c; i += THREADS) {
        const unsigned bits = tbits[i], idx = tidx[i];
        const uint64_t key = ((uint64_t)(bits & 0x7FFFFFFFu) << 32) | (uint64_t)(~idx);
        int rank = 0;
        for (int j = 0; j < c; ++j) {
            const uint64_t kj = ((uint64_t)(tbits[j] & 0x7FFFFFFFu) << 32) | (uint64_t)(~tidx[j]);
            rank += (kj > key) ? 1 : 0;
        }
        if (rank < need) rout[idx] = __uint_as_float(bits);
    }
}

// ---- fallback: self-contained exact solve for flagged rows (normally no-op) --
__global__ __launch_bounds__(THREADS) void fallback_kernel(const float* __restrict__ x,
                                                           float* __restrict__ out,
                                                           const int* __restrict__ topk,
                                                           const int* __restrict__ row_flag) {
    const int row = blockIdx.x;
    if (!row_flag[row]) return;
    const int t = threadIdx.x;
    const unsigned K = (unsigned)(*topk);
    const float4* xr = (const float4*)(x + (size_t)row * ROW_N);
    float* rout = out + (size_t)row * ROW_N;   // already zero-filled by passA

    __shared__ unsigned h[NBUCKET];          // 16 KiB coarse hist
    __shared__ unsigned tidx[FB_TIE_CAP];    // 16 KiB
    __shared__ unsigned tbits[FB_TIE_CAP];   // 16 KiB
    __shared__ unsigned partial[THREADS];
    __shared__ unsigned excl[THREADS];
    __shared__ unsigned tcnt;
    __shared__ int sb, sneed;
    for (int i = t; i < NBUCKET; i += THREADS) h[i] = 0;
    if (t == 0) tcnt = 0;
    __syncthreads();

    for (int i4 = t; i4 < ROW_N / 4; i4 += THREADS) {
        const float4 v = xr[i4];
        atomicAdd(&h[(__float_as_uint(v.x) & 0x7FFFFFFFu) >> KSHIFT], 1u);
        atomicAdd(&h[(__float_as_uint(v.y) & 0x7FFFFFFFu) >> KSHIFT], 1u);
        atomicAdd(&h[(__float_as_uint(v.z) & 0x7FFFFFFFu) >> KSHIFT], 1u);
        atomicAdd(&h[(__float_as_uint(v.w) & 0x7FFFFFFFu) >> KSHIFT], 1u);
    }
    __syncthreads();

    const int PER = NBUCKET / THREADS;   // 16
    unsigned s = 0;
#pragma unroll
    for (int i = 0; i < PER; ++i) s += h[NBUCKET - 1 - (t * PER + i)];
    partial[t] = s;
    __syncthreads();
    if (t == 0) {
        unsigned c = 0;
        for (int i = 0; i < THREADS; ++i) { excl[i] = c; c += partial[i]; }
    }
    __syncthreads();
    unsigned cum = excl[t];
#pragma unroll
    for (int i = 0; i < PER; ++i) {
        const int bucket = NBUCKET - 1 - (t * PER + i);
        const unsigned c = h[bucket];
        if (cum < K && cum + c >= K) { sb = bucket; sneed = (int)(K - cum); }
        cum += c;
    }
    __syncthreads();
    const int b = sb;
    const int need = sneed;

    for (int i4 = t; i4 < ROW_N / 4; i4 += THREADS) {
        const float4 v = xr[i4];
        const unsigned bits4[4] = {__float_as_uint(v.x), __float_as_uint(v.y),
                                   __float_as_uint(v.z), __float_as_uint(v.w)};
#pragma unroll
        for (int c = 0; c < 4; ++c) {
            const int key = (int)((bits4[c] & 0x7FFFFFFFu) >> KSHIFT);
            if (key > b) {
                rout[i4 * 4 + c] = __uint_as_float(bits4[c]);
            } else if (key == b) {
                const unsigned p = atomicAdd(&tcnt, 1u);
                if (p < FB_TIE_CAP) { tidx[p] = (unsigned)(i4 * 4 + c); tbits[p] = bits4[c]; }
            }
        }
    }
    __syncthreads();
    const int c = (int)(tcnt < (unsigned)FB_TIE_CAP ? tcnt : (unsigned)FB_TIE_CAP);
    for (int i = t; i < c; i += THREADS) {
        const unsigned bits = tbits[i], idx = tidx[i];
        const uint64_t key = ((uint64_t)(bits & 0x7FFFFFFFu) << 32) | (uint64_t)(~idx);
        int rank = 0;
        for (int j = 0; j < c; ++j) {
            const uint64_t kj = ((uint64_t)(tbits[j] & 0x7FFFFFFFu) << 32) | (uint64_t)(~tidx[j]);
            rank += (kj > key) ? 1 : 0;
        }
        if (rank < need) rout[idx] = __uint_as_float(bits);
    }
}

extern "C" void kernel_launch(void* const* d_in, const int* in_sizes, int n_in,
                              void* d_out, int out_size, void* d_ws, size_t ws_size,
                              hipStream_t stream) {
    const float* x = (const float*)d_in[0];
    const int* topk = (const int*)d_in[1];
    float* out = (float*)d_out;
    char* ws = (char*)d_ws;

    unsigned* cand_count = (unsigned*)(ws + OFF_CNT);
    unsigned* row_oflow  = (unsigned*)(ws + OFF_OFL);
    int* row_flag        = (int*)(ws + OFF_FLG);
    uint2* cand          = (uint2*)(ws + OFF_CAND);

    // zero counters + flags only (ws is re-poisoned to 0xAA before each run)
    hipMemsetAsync(ws, 0, MEMSET_BYTES, stream);

    dim3 gridA(BLOCKS_PER_ROW, B);  // 16 x 128 = 2048 blocks
    passA_kernel<<<gridA, THREADS, 0, stream>>>(x, out, cand_count, row_oflow, cand);
    select_scatter_kernel<<<B, THREADS, 0, stream>>>(cand, cand_count, row_oflow,
                                                     topk, out, row_flag);
    fallback_kernel<<<B, THREADS, 0, stream>>>(x, out, topk, row_flag);
}

// Round 6
// 296.253 us; speedup vs baseline: 1.1551x; 1.0425x over previous
//
#include <hip/hip_runtime.h>
#include <stdint.h>

// Problem constants (fixed by the reference): x is (128,1,512,512) fp32, k=2048.
#define B        128
#define ROW_N    262144                 // 512*512 elements per row
#define THREADS  256
#define BLOCKS_PER_ROW 16
#define BLK_CHUNK (ROW_N / BLOCKS_PER_ROW)   // 16384 floats per block
#define WAVE_CHUNK 4096                      // floats per wave (4 waves/block)
#define WAVE_CAP 512                         // per-wave candidate cap (mean 184, +25 sigma)

// Speculative exact pre-filter: keep ALL elements with |x| >= 2.0.
// For the fixed N(0,1) input: k-th |x| ~= 2.66; >=2.0 population ~11.9k +- 107
// per row. n >= K guarantees the exact top-k lies within the candidate set.
// Any violation (per-wave cap, row cap, n < K) flags the row -> exact fallback.
#define B0_BITS  0x40000000u  // bit pattern of 2.0f (abs-bits compare)
#define CAND_CAP 16384        // per-row candidate capacity (+41 sigma)
#define FKSHIFT  17           // 14-bit fine key for tie resolution
#define FB0      8192         // (B0_BITS >> FKSHIFT)
#define NFB      8192         // fine buckets [8192, 16384)
#define TIE_CAP  2048         // ties in one fine bucket (mean ~190)
#define THREADS_SS 512        // select_scatter block size
// fallback (normally never runs)
#define KSHIFT   19
#define NBUCKET  4096
#define FB_TIE_CAP 4096

// workspace layout (bytes)
#define OFF_CNT  0                         // per-row candidate counters (B u32)
#define OFF_OFL  512                       // per-row overflow flags (B u32)
#define OFF_FLG  1024                      // per-row fallback flag (B int)
#define OFF_CAND 4096                      // B * CAND_CAP * uint2 = 16 MiB
#define MEMSET_BYTES 1536

typedef float vfloat4 __attribute__((ext_vector_type(4)));

// ---- pass A: ONE barrier-free pass. zero-fill out + wave-compact |x|>=2 -----
// No __syncthreads, no LDS atomics, no per-element global atomics. Each wave
// owns a contiguous 4096-float segment and a private 512-entry LDS buffer;
// compaction via ballot + wave-uniform counter; one global atomic at the end.
__global__ __launch_bounds__(THREADS) void scan_zero_kernel(const float* __restrict__ x,
                                                            float* __restrict__ out,
                                                            unsigned* __restrict__ cand_count,
                                                            unsigned* __restrict__ row_oflow,
                                                            uint2* __restrict__ cand) {
    __shared__ uint2 wbuf[THREADS / 64][WAVE_CAP];   // 16 KiB, wave-private slices
    const int t = threadIdx.x;
    const int w = t >> 6;
    const int lane = t & 63;
    const unsigned long long lt = (1ull << lane) - 1ull;
    const int row = blockIdx.y;
    const int wbase = blockIdx.x * BLK_CHUNK + w * WAVE_CHUNK;  // float offset in row
    const float4* src = (const float4*)(x + (size_t)row * ROW_N + wbase);
    vfloat4* dst = (vfloat4*)(out + (size_t)row * ROW_N + wbase);
    uint2* wb = wbuf[w];
    unsigned wcnt = 0;   // wave-uniform (derived from ballots only)
    const vfloat4 z = {0.f, 0.f, 0.f, 0.f};

    for (int g = 0; g < 4; ++g) {
        // 4 independent coalesced loads in flight; zero-stores are constant
        // (no dependency on the loads) and nontemporal (don't pollute L3).
        float4 v[4];
#pragma unroll
        for (int u = 0; u < 4; ++u) v[u] = src[(g * 4 + u) * 64 + lane];
#pragma unroll
        for (int u = 0; u < 4; ++u)
            __builtin_nontemporal_store(z, &dst[(g * 4 + u) * 64 + lane]);
#pragma unroll
        for (int u = 0; u < 4; ++u) {
            const unsigned fbase = (unsigned)(wbase + ((g * 4 + u) * 64 + lane) * 4);
            const unsigned bb[4] = {__float_as_uint(v[u].x), __float_as_uint(v[u].y),
                                    __float_as_uint(v[u].z), __float_as_uint(v[u].w)};
#pragma unroll
            for (int c = 0; c < 4; ++c) {
                const bool pred = (bb[c] & 0x7FFFFFFFu) >= B0_BITS;   // ~4.5%
                const unsigned long long mask = __ballot(pred);
                if (pred) {
                    const unsigned p = wcnt + (unsigned)__popcll(mask & lt);
                    if (p < WAVE_CAP) wb[p] = make_uint2(fbase + (unsigned)c, bb[c]);
                }
                wcnt += (unsigned)__popcll(mask);
            }
        }
    }

    // final flush: one global atomic per wave
    const unsigned total = wcnt < WAVE_CAP ? wcnt : WAVE_CAP;
    unsigned base = 0;
    if (lane == 0) {
        base = atomicAdd(&cand_count[row], wcnt);   // true count (gap/oflow detect)
        if (wcnt > WAVE_CAP) row_oflow[row] = 1u;
    }
    base = __shfl(base, 0);
    uint2* rcand = cand + (size_t)row * CAND_CAP;
    for (unsigned i = (unsigned)lane; i < total; i += 64) {
        const unsigned gpos = base + i;
        if (gpos < CAND_CAP) rcand[gpos] = wb[i];
    }
}

// -- select+scatter fused: per row, hist over candidates only, exact top-k -----
__global__ __launch_bounds__(THREADS_SS) void select_scatter_kernel(
        const uint2* __restrict__ cand, const unsigned* __restrict__ cand_count,
        const unsigned* __restrict__ row_oflow, const int* __restrict__ topk,
        float* __restrict__ out, int* __restrict__ row_flag) {
    const int row = blockIdx.x;
    const int t = threadIdx.x;
    const unsigned K = (unsigned)(*topk);
    const unsigned n = cand_count[row];
    const unsigned of = row_oflow[row];

    __shared__ unsigned h[NFB];          // 32 KiB fine-bucket hist
    __shared__ unsigned tidx[TIE_CAP];   // 8 KiB
    __shared__ unsigned tbits[TIE_CAP];  // 8 KiB
    __shared__ unsigned partial[THREADS_SS];
    __shared__ unsigned excl[THREADS_SS];
    __shared__ unsigned tcnt;
    __shared__ int sb, sneed;

    if (n < K || n > (unsigned)CAND_CAP || of) {   // block-uniform
        if (t == 0) row_flag[row] = 1;
        return;
    }
    for (int i = t; i < NFB; i += THREADS_SS) h[i] = 0;
    if (t == 0) tcnt = 0;
    __syncthreads();

    const uint2* rc = cand + (size_t)row * CAND_CAP;
    for (unsigned i = (unsigned)t; i < n; i += THREADS_SS) {
        const uint2 e = rc[i];
        atomicAdd(&h[((e.y & 0x7FFFFFFFu) >> FKSHIFT) - FB0], 1u);
    }
    __syncthreads();

    // suffix scan from the top fine bucket
    const int PER = NFB / THREADS_SS;   // 16
    unsigned s = 0;
#pragma unroll
    for (int i = 0; i < PER; ++i) s += h[NFB - 1 - (t * PER + i)];
    partial[t] = s;
    __syncthreads();
    if (t == 0) {
        unsigned c = 0;
        for (int i = 0; i < THREADS_SS; ++i) { excl[i] = c; c += partial[i]; }
    }
    __syncthreads();
    unsigned cum = excl[t];
#pragma unroll
    for (int i = 0; i < PER; ++i) {
        const int brel = NFB - 1 - (t * PER + i);
        const unsigned c = h[brel];
        if (cum < K && cum + c >= K) {   // unique crossing
            sb = brel + FB0;
            sneed = (int)(K - cum);
        }
        cum += c;
    }
    __syncthreads();
    const int b = sb;
    const int need = sneed;
    if (h[b - FB0] > (unsigned)TIE_CAP) {   // block-uniform; before any writes
        if (t == 0) row_flag[row] = 1;
        return;
    }

    // scatter winners above the tie bucket; collect ties
    float* rout = out + (size_t)row * ROW_N;
    for (unsigned i = (unsigned)t; i < n; i += THREADS_SS) {
        const uint2 e = rc[i];
        const int fk = (int)((e.y & 0x7FFFFFFFu) >> FKSHIFT);
        if (fk > b) {
            rout[e.x] = __uint_as_float(e.y);
        } else if (fk == b) {
            const unsigned p = atomicAdd(&tcnt, 1u);
            tidx[p] = e.x; tbits[p] = e.y;   // p < TIE_CAP guaranteed (hist check)
        }
    }
    __syncthreads();

    // exact rank among ties: desc |x| bits, asc index (matches lax.top_k)
    const int c = (int)tcnt;
    for (int i = t; i < c; i += THREADS_SS) {
        const unsigned bits = tbits[i], idx = tidx[i];
        const uint64_t key = ((uint64_t)(bits & 0x7FFFFFFFu) << 32) | (uint64_t)(~idx);
        int rank = 0;
        for (int j = 0; j < c; ++j) {
            const uint64_t kj = ((uint64_t)(tbits[j] & 0x7FFFFFFFu) << 32) | (uint64_t)(~tidx[j]);
            rank += (kj > key) ? 1 : 0;
        }
        if (rank < need) rout[idx] = __uint_as_float(bits);
    }
}

// ---- fallback: self-contained exact solve for flagged rows (normally no-op) --
__global__ __launch_bounds__(THREADS) void fallback_kernel(const float* __restrict__ x,
                                                           float* __restrict__ out,
                                                           const int* __restrict__ topk,
                                                           const int* __restrict__ row_flag) {
    const int row = blockIdx.x;
    if (!row_flag[row]) return;
    const int t = threadIdx.x;
    const unsigned K = (unsigned)(*topk);
    const float4* xr = (const float4*)(x + (size_t)row * ROW_N);
    float* rout = out + (size_t)row * ROW_N;   // already zero-filled by scan_zero

    __shared__ unsigned h[NBUCKET];          // 16 KiB coarse hist
    __shared__ unsigned tidx[FB_TIE_CAP];    // 16 KiB
    __shared__ unsigned tbits[FB_TIE_CAP];   // 16 KiB
    __shared__ unsigned partial[THREADS];
    __shared__ unsigned excl[THREADS];
    __shared__ unsigned tcnt;
    __shared__ int sb, sneed;
    for (int i = t; i < NBUCKET; i += THREADS) h[i] = 0;
    if (t == 0) tcnt = 0;
    __syncthreads();

    for (int i4 = t; i4 < ROW_N / 4; i4 += THREADS) {
        const float4 v = xr[i4];
        atomicAdd(&h[(__float_as_uint(v.x) & 0x7FFFFFFFu) >> KSHIFT], 1u);
        atomicAdd(&h[(__float_as_uint(v.y) & 0x7FFFFFFFu) >> KSHIFT], 1u);
        atomicAdd(&h[(__float_as_uint(v.z) & 0x7FFFFFFFu) >> KSHIFT], 1u);
        atomicAdd(&h[(__float_as_uint(v.w) & 0x7FFFFFFFu) >> KSHIFT], 1u);
    }
    __syncthreads();

    const int PER = NBUCKET / THREADS;   // 16
    unsigned s = 0;
#pragma unroll
    for (int i = 0; i < PER; ++i) s += h[NBUCKET - 1 - (t * PER + i)];
    partial[t] = s;
    __syncthreads();
    if (t == 0) {
        unsigned c = 0;
        for (int i = 0; i < THREADS; ++i) { excl[i] = c; c += partial[i]; }
    }
    __syncthreads();
    unsigned cum = excl[t];
#pragma unroll
    for (int i = 0; i < PER; ++i) {
        const int bucket = NBUCKET - 1 - (t * PER + i);
        const unsigned c = h[bucket];
        if (cum < K && cum + c >= K) { sb = bucket; sneed = (int)(K - cum); }
        cum += c;
    }
    __syncthreads();
    const int b = sb;
    const int need = sneed;

    for (int i4 = t; i4 < ROW_N / 4; i4 += THREADS) {
        const float4 v = xr[i4];
        const unsigned bits4[4] = {__float_as_uint(v.x), __float_as_uint(v.y),
                                   __float_as_uint(v.z), __float_as_uint(v.w)};
#pragma unroll
        for (int c = 0; c < 4; ++c) {
            const int key = (int)((bits4[c] & 0x7FFFFFFFu) >> KSHIFT);
            if (key > b) {
                rout[i4 * 4 + c] = __uint_as_float(bits4[c]);
            } else if (key == b) {
                const unsigned p = atomicAdd(&tcnt, 1u);
                if (p < FB_TIE_CAP) { tidx[p] = (unsigned)(i4 * 4 + c); tbits[p] = bits4[c]; }
            }
        }
    }
    __syncthreads();
    const int c = (int)(tcnt < (unsigned)FB_TIE_CAP ? tcnt : (unsigned)FB_TIE_CAP);
    for (int i = t; i < c; i += THREADS) {
        const unsigned bits = tbits[i], idx = tidx[i];
        const uint64_t key = ((uint64_t)(bits & 0x7FFFFFFFu) << 32) | (uint64_t)(~idx);
        int rank = 0;
        for (int j = 0; j < c; ++j) {
            const uint64_t kj = ((uint64_t)(tbits[j] & 0x7FFFFFFFu) << 32) | (uint64_t)(~tidx[j]);
            rank += (kj > key) ? 1 : 0;
        }
        if (rank < need) rout[idx] = __uint_as_float(bits);
    }
}

extern "C" void kernel_launch(void* const* d_in, const int* in_sizes, int n_in,
                              void* d_out, int out_size, void* d_ws, size_t ws_size,
                              hipStream_t stream) {
    const float* x = (const float*)d_in[0];
    const int* topk = (const int*)d_in[1];
    float* out = (float*)d_out;
    char* ws = (char*)d_ws;

    unsigned* cand_count = (unsigned*)(ws + OFF_CNT);
    unsigned* row_oflow  = (unsigned*)(ws + OFF_OFL);
    int* row_flag        = (int*)(ws + OFF_FLG);
    uint2* cand          = (uint2*)(ws + OFF_CAND);

    // zero counters + flags only (ws is re-poisoned to 0xAA before each run)
    hipMemsetAsync(ws, 0, MEMSET_BYTES, stream);

    dim3 gridA(BLOCKS_PER_ROW, B);  // 16 x 128 = 2048 blocks, 8/CU, 100% occ
    scan_zero_kernel<<<gridA, THREADS, 0, stream>>>(x, out, cand_count, row_oflow, cand);
    select_scatter_kernel<<<B, THREADS_SS, 0, stream>>>(cand, cand_count, row_oflow,
                                                        topk, out, row_flag);
    fallback_kernel<<<B, THREADS, 0, stream>>>(x, out, topk, row_flag);
}